// Round 4
// baseline (136.711 us; speedup 1.0000x reference)
//
#include <hip/hip_runtime.h>
#include <cmath>

#define NPIX   289          // 17*17
#define NU     10           // unique GLCM offsets (12 slots, 2 dups)
#define NF     70           // 4 stat + 6 hist + 60 glcm
#define NFP    80           // padded per-batch stride (floats): 320 B, 64B-line aligned
#define NWX    60
#define IMG_W  256
#define IMG_HW 65536
#define NWIN   28800        // 8 * 60 * 60
#define ACC    560          // logical outputs (8*70)
#define ACCP   640          // padded accumulator stride per set (8*80)
#define WPB    2            // waves per block
#define WPW    4            // windows per wave (prefetch-pipelined)
#define NBLK   (NWIN / (WPB * WPW))   // 3600
#define GLS    29           // padded LDS stride for 28-entry GLCM triangles

// slot -> unique offset index for the 12 reference offsets
__device__ __constant__ int c_s2u[12] = {0,1,2,3,4,1,5,3,6,7,8,9};

// unique offsets (dr, dc); flat-shift joff = dr*17 + dc
constexpr int JOFF[NU] = {1, 18, 17, 16, 2, 34, 3, 36, 51, 32};
// 1/(2*npairs), npairs = (17-dr)*(17-|dc|)
constexpr float INV2N[NU] = {1.f/544.f, 1.f/512.f, 1.f/544.f, 1.f/512.f, 1.f/510.f,
                             1.f/510.f, 1.f/476.f, 1.f/450.f, 1.f/476.f, 1.f/450.f};

// column-validity masks per distinct dc (target-column constraint).
struct CMs { unsigned m[10]; };
constexpr CMs mkcm(int dc) {
    CMs c{};
    for (int t = 0; t < NPIX; ++t) {
        int col = t % 17;
        bool ok = (dc > 0) ? (col >= dc) : (col <= 16 + dc);
        if (ok) c.m[t >> 5] |= 1u << (t & 31);
    }
    return c;
}
constexpr CMs CMp1 = mkcm(1), CMp2 = mkcm(2), CMp3 = mkcm(3);
constexpr CMs CMn1 = mkcm(-1), CMn2 = mkcm(-2);

// fused per-element constants for the upper-triangle feature pass.
struct alignas(32) FtE { float w, d2, inv, si, sii, sij, q0, q1; };
struct FtTab { FtE e[28]; };
constexpr FtTab mkft() {
    FtTab t{};
    int n = 0;
    for (int a = 1; a <= 7; ++a)
        for (int b = a; b <= 7; ++b) {
            int i = a - 1, j = b - 1;
            float w  = (a == b) ? 1.f : 2.f;
            float d2 = (float)((i - j) * (i - j));
            t.e[n] = FtE{w, d2, 1.f / (1.f + d2),
                         0.5f * (float)(i + j),
                         0.5f * (float)(i * i + j * j),
                         (float)(i * j), 0.f, 0.f};
            ++n;
        }
    return t;
}
__device__ __constant__ FtTab c_ft = mkft();

// GLCM pair count for one offset: popc(ma & shifted(mv)); word count pruned per offset.
template<int O>
__device__ __forceinline__ int gcnt(const unsigned* __restrict__ M,
                                    const unsigned* __restrict__ ma) {
    constexpr int wq = JOFF[O] >> 5;
    constexpr int rr = JOFF[O] & 31;
    constexpr int nw = (288 - JOFF[O]) / 32 + 1;
    int acc = 0;
#pragma unroll
    for (int w = 0; w < nw; ++w) {
        unsigned sh = (rr == 0) ? M[w + wq]
                                : __builtin_amdgcn_alignbit(M[w + wq + 1], M[w + wq], rr);
        acc += __popc(ma[w] & sh);
    }
    return acc;
}

// ---- DPP wave-64 reductions: 6 VALU ops, no LDS pipe ----
#define DPP_F(oldv, srcv, ctrl, rm) \
    __int_as_float(__builtin_amdgcn_update_dpp((oldv), __float_as_int(srcv), (ctrl), (rm), 0xF, false))

__device__ __forceinline__ float dpp_wsum(float v) {
    v += DPP_F(0, v, 0x111, 0xF);
    v += DPP_F(0, v, 0x112, 0xF);
    v += DPP_F(0, v, 0x114, 0xF);
    v += DPP_F(0, v, 0x118, 0xF);
    v += DPP_F(0, v, 0x142, 0xA);
    v += DPP_F(0, v, 0x143, 0xC);
    return __int_as_float(__builtin_amdgcn_readlane(__float_as_int(v), 63));
}
__device__ __forceinline__ float dpp_wmax(float v) {
    v = fmaxf(v, DPP_F(__float_as_int(v), v, 0x111, 0xF));
    v = fmaxf(v, DPP_F(__float_as_int(v), v, 0x112, 0xF));
    v = fmaxf(v, DPP_F(__float_as_int(v), v, 0x114, 0xF));
    v = fmaxf(v, DPP_F(__float_as_int(v), v, 0x118, 0xF));
    v = fmaxf(v, DPP_F(__float_as_int(v), v, 0x142, 0xA));
    v = fmaxf(v, DPP_F(__float_as_int(v), v, 0x143, 0xC));
    return __int_as_float(__builtin_amdgcn_readlane(__float_as_int(v), 63));
}
__device__ __forceinline__ float dpp_wmin(float v) {
    v = fminf(v, DPP_F(__float_as_int(v), v, 0x111, 0xF));
    v = fminf(v, DPP_F(__float_as_int(v), v, 0x112, 0xF));
    v = fminf(v, DPP_F(__float_as_int(v), v, 0x114, 0xF));
    v = fminf(v, DPP_F(__float_as_int(v), v, 0x118, 0xF));
    v = fminf(v, DPP_F(__float_as_int(v), v, 0x142, 0xA));
    v = fminf(v, DPP_F(__float_as_int(v), v, 0x143, 0xC));
    return __int_as_float(__builtin_amdgcn_readlane(__float_as_int(v), 63));
}

__device__ __forceinline__ float bperm_f(int addr, float v) {
    return __int_as_float(__builtin_amdgcn_ds_bpermute(addr, __float_as_int(v)));
}

__global__ __launch_bounds__(128, 8) void feat_kernel(const float* __restrict__ x,
                                                      float* __restrict__ ptot,
                                                      float* __restrict__ pnz,
                                                      int setmask) {
    __shared__ float s_g[WPB][NU * GLS];
    __shared__ float s_uf[WPB][5][NU];
    __shared__ float s_s10[WPB][10];

    const int lane = threadIdx.x & 63;
    const int wid  = threadIdx.x >> 6;
    // XCD-aware mapping: blockIdx%8 == XCD == batch -> each XCD's L2 sees one 256KB channel.
    const int b     = blockIdx.x & 7;
    const int lbid  = blockIdx.x >> 3;                 // 0..449
    const int rem0  = lbid * (WPB * WPW) + wid * WPW;  // multiple of 4, < 3600
    const int wy    = rem0 / NWX;
    const int wx0   = rem0 - wy * NWX;                 // multiple of 4 (60%4==0 -> no row wrap)
    const int widx0 = b * 3600 + rem0;
    const float* img0 = x + (size_t)(b * 3 + 1) * IMG_HW + (wy * 4) * IMG_W + wx0 * 4;

    float* gl  = s_g[wid];
    float (*uf)[NU] = s_uf[wid];
    float* s10 = s_s10[wid];

    // ---- wave-invariant lane mappings (hoisted out of the window loop) ----
    const int l49 = (lane < 49) ? lane : 48;
    const int ba  = l49 / 7 + 1;
    const int bb  = l49 - (ba - 1) * 7 + 1;
    const int partner = (bb - 1) * 7 + (ba - 1);
    const int paddr   = partner << 2;
    const unsigned long long xm0a = (ba & 1) ? 0ull : ~0ull;
    const unsigned long long xm1a = (ba & 2) ? 0ull : ~0ull;
    const unsigned long long xm2a = (ba & 4) ? 0ull : ~0ull;
    const int amin  = min(ba, bb);
    const int idx28 = 8 * (amin - 1) - ((amin * (amin - 1)) >> 1) + (max(ba, bb) - amin);
    const bool wr   = (lane < 49) && (ba <= bb);
    const int fo  = lane & 15;
    const int sub = lane >> 4;
    const int xa16 = (lane ^ 16) << 2;
    const int xa32 = (lane ^ 32) << 2;
    const int obase = b * NFP;

    // per-lane load offsets (identical for all 4 windows; windows differ by +4 floats)
    int off[5];
#pragma unroll
    for (int k = 0; k < 5; ++k) {
        int t = lane + k * 64;
        int r = t / 17;
        off[k] = r * (IMG_W - 17) + t;     // r*256 + c
    }
    const bool v4 = (lane < NPIX - 256);   // lane < 33 (k=4 validity)

    // ---- per-window body (everything after the loads) ----
    auto PROC = [&](const float (&pv)[5], int widx) {
        float lsum = 0.f, lss = 0.f, lmax = -1e30f, lmin = 1e30f;
        int n = 0, c1 = 0, c2 = 0, c3 = 0, c4 = 0, c5 = 0, c6 = 0;
        unsigned ma32[10];
#pragma unroll
        for (int k = 0; k < 5; ++k) {
            float p = pv[k];
            float val = (p < 10.f) ? 0.f : p;
            if (k == 4) val = v4 ? val : 0.f;          // out-of-window lanes contribute 0
            int qq = (int)fmaf(val, 0.025f, 0.8125f);  // 0..7, 0 iff val==0
            lsum += val;
            float d = (val != 0.f) ? (val - 127.5f) : 0.f;
            lss = fmaf(d, d, lss);
            lmax = fmaxf(lmax, val);
            lmin = fminf(lmin, (val != 0.f) ? val : 1e30f);
            unsigned long long p0 = __ballot(qq & 1);
            unsigned long long p1 = __ballot(qq & 2);
            unsigned long long p2 = __ballot(qq & 4);
            n  += __popcll(p0 | p1 | p2);
            c1 += __popcll(p0 & ~p1 & ~p2);
            c2 += __popcll(~p0 & p1 & ~p2);
            c3 += __popcll(p0 & p1 & ~p2);
            c4 += __popcll(~p0 & ~p1 & p2);
            c5 += __popcll(p0 & ~p1 & p2);
            c6 += __popcll(~p0 & p1 & p2);
            unsigned long long mA = (p0 ^ xm0a) & (p1 ^ xm1a) & (p2 ^ xm2a);
            ma32[2*k]   = (unsigned)mA;
            ma32[2*k+1] = (unsigned)(mA >> 32);
        }

        if (n == 0) return;   // empty window contributes nothing

        // mB fetch on the LDS pipe; latency hides under the DPP stat reductions
        unsigned mv0[10];
#pragma unroll
        for (int w = 0; w < 10; ++w)
            mv0[w] = (unsigned)__builtin_amdgcn_ds_bpermute(paddr, (int)ma32[w]);

        const float fn   = (float)n;
        const float sum  = dpp_wsum(lsum);
        const float ss   = dpp_wsum(lss);
        const float mx   = dpp_wmax(lmax);
        const float mn   = dpp_wmin(lmin);
        const float mean = sum / fn;
        const float mc   = mean - 127.5f;
        const float var  = fmaxf(ss / fn - mc * mc, 0.f);
        const float stdv = sqrtf(var);

        if (lane == 0) {
            s10[0] = mean;
            s10[1] = stdv;
            s10[2] = (mx - mean) / (stdv + 1e-9f);
            s10[3] = (mean - mn) / (stdv + 1e-9f);
            s10[4] = (float)c1 * (1.f / 289.f);
            s10[5] = (float)c2 * (1.f / 289.f);
            s10[6] = (float)c3 * (1.f / 289.f);
            s10[7] = (float)c4 * (1.f / 289.f);
            s10[8] = (float)c5 * (1.f / 289.f);
            s10[9] = (float)c6 * (1.f / 289.f);
        }

        // GLCM counts: column-masked mv0, shared per distinct dc
        int cnta[NU];
        {
            cnta[2] = gcnt<2>(mv0, ma32);
            cnta[5] = gcnt<5>(mv0, ma32);
            cnta[8] = gcnt<8>(mv0, ma32);
            unsigned mv[10];
#pragma unroll
            for (int w = 0; w < 10; ++w) mv[w] = mv0[w] & CMp1.m[w];
            cnta[0] = gcnt<0>(mv, ma32);
            cnta[1] = gcnt<1>(mv, ma32);
#pragma unroll
            for (int w = 0; w < 10; ++w) mv[w] = mv0[w] & CMp2.m[w];
            cnta[4] = gcnt<4>(mv, ma32);
            cnta[7] = gcnt<7>(mv, ma32);
#pragma unroll
            for (int w = 0; w < 10; ++w) mv[w] = mv0[w] & CMp3.m[w];
            cnta[6] = gcnt<6>(mv, ma32);
#pragma unroll
            for (int w = 0; w < 10; ++w) mv[w] = mv0[w] & CMn1.m[w];
            cnta[3] = gcnt<3>(mv, ma32);
#pragma unroll
            for (int w = 0; w < 10; ++w) mv[w] = mv0[w] & CMn2.m[w];
            cnta[9] = gcnt<9>(mv, ma32);
        }

        // symmetrize via bpermute, stage upper triangle into LDS
#pragma unroll
        for (int o = 0; o < NU; ++o) {
            int pc = __builtin_amdgcn_ds_bpermute(paddr, cnta[o]);
            float g = (float)(cnta[o] + pc) * INV2N[o];
            if (wr) gl[o * GLS + idx28] = g;
        }

        // features over upper triangle: 4 sub-lanes per offset, 7 iters
        float gsum=0.f, entU=0.f, conU=0.f, homU=0.f, g2=0.f, siU=0.f, siiU=0.f, sijU=0.f;
        if (fo < NU) {
#pragma unroll
            for (int i = 0; i < 7; ++i) {
                const int e = sub + 4 * i;
                FtE c = c_ft.e[e];
                float g  = gl[fo * GLS + e];
                float gw = g * c.w;
                float l  = __log2f(g + 1e-8f);
                gsum += gw;
                entU  = fmaf(gw, l,      entU);
                conU  = fmaf(gw, c.d2,   conU);
                homU  = fmaf(gw, c.inv,  homU);
                g2    = fmaf(gw, g,      g2);
                siU   = fmaf(gw, c.si,   siU);
                siiU  = fmaf(gw, c.sii,  siiU);
                sijU  = fmaf(gw, c.sij,  sijU);
            }
        }
        gsum += bperm_f(xa16, gsum);  entU += bperm_f(xa16, entU);
        conU += bperm_f(xa16, conU);  homU += bperm_f(xa16, homU);
        g2   += bperm_f(xa16, g2);    siU  += bperm_f(xa16, siU);
        siiU += bperm_f(xa16, siiU);  sijU += bperm_f(xa16, sijU);
        gsum += bperm_f(xa32, gsum);  entU += bperm_f(xa32, entU);
        conU += bperm_f(xa32, conU);  homU += bperm_f(xa32, homU);
        g2   += bperm_f(xa32, g2);    siU  += bperm_f(xa32, siU);
        siiU += bperm_f(xa32, siiU);  sijU += bperm_f(xa32, sijU);

        if (fo < NU && sub == 0) {
            const float invg = 1.f / fmaxf(gsum, 1e-12f);
            const float si  = siU  * invg;
            const float sii = siiU * invg;
            const float sij = sijU * invg;
            const float varg = fmaxf(sii - si * si, 0.f);
            const float cov  = sij - si * si;
            uf[0][fo] = conU * invg;
            uf[1][fo] = homU * invg;
            uf[2][fo] = sqrtf(g2) * invg;
            uf[3][fo] = (varg < 1e-15f) ? 1.f : cov / fmaxf(varg, 1e-15f);
            uf[4][fo] = -entU;
        }

        // accumulate into XCD-private, line-aligned partial sets
        const int setbase = (widx & setmask) * ACCP;
        for (int t = lane; t < NF; t += 64) {
            float f;
            if (t < 10) {
                f = s10[t];
            } else {
                int u    = t - 10;
                int grp  = u / 12;
                int slot = u - grp * 12;
                f = uf[grp][c_s2u[slot]];
            }
            atomicAdd(&ptot[setbase + obase + t], f);
            if (t >= 4 && t <= 9 && f != 0.f)
                atomicAdd(&pnz[setbase + obase + t], 1.f);
        }
        if (lane == 0)
            atomicAdd(&pnz[setbase + obase], 1.f);   // window count (n>0)
    };

    // ---- 4-window software pipeline: loads for window i+1 in flight during PROC(i) ----
#define LOADW(buf, iw) { \
        const float* ip = img0 + (iw) * 4; \
        buf[0] = ip[off[0]]; buf[1] = ip[off[1]]; buf[2] = ip[off[2]]; \
        buf[3] = ip[off[3]]; buf[4] = ip[off[4]]; }

    float bufA[5], bufB[5];
    LOADW(bufA, 0)
    LOADW(bufB, 1)
    PROC(bufA, widx0 + 0);
    LOADW(bufA, 2)
    PROC(bufB, widx0 + 1);
    LOADW(bufB, 3)
    PROC(bufA, widx0 + 2);
    PROC(bufB, widx0 + 3);
#undef LOADW
}

__global__ void reduce_kernel(const float* __restrict__ ptot,
                              const float* __restrict__ pnz,
                              float* __restrict__ out, int nset) {
    int t = blockIdx.x * blockDim.x + threadIdx.x;
    if (t >= ACC) return;
    int b = t / NF;
    int u = t - b * NF;
    int pa = b * NFP + u;
    bool hist = (u >= 4 && u <= 9);
    int nzidx = hist ? pa : b * NFP;     // hardwired features use the window count
    float s = 0.f, nz = 0.f;
    for (int k = 0; k < nset; ++k) {
        s  += ptot[(size_t)k * ACCP + pa];
        nz += pnz[(size_t)k * ACCP + nzidx];
    }
    out[t] = s / (nz + 1e-9f);
}

extern "C" void kernel_launch(void* const* d_in, const int* in_sizes, int n_in,
                              void* d_out, int out_size, void* d_ws, size_t ws_size,
                              hipStream_t stream) {
    (void)in_sizes; (void)n_in; (void)out_size;
    const float* x = (const float*)d_in[0];
    float* out = (float*)d_out;

    const size_t per_set = (size_t)2 * ACCP * sizeof(float);   // 5120 B
    int maxs = (ws_size >= per_set) ? (int)(ws_size / per_set) : 1;
    int nset = 1;
    while ((nset * 2) <= maxs && nset < 64) nset <<= 1;

    float* ptot = (float*)d_ws;
    float* pnz  = ptot + (size_t)nset * ACCP;

    hipMemsetAsync(d_ws, 0, (size_t)nset * per_set, stream);
    feat_kernel<<<dim3(NBLK), dim3(WPB * 64), 0, stream>>>(x, ptot, pnz, nset - 1);
    reduce_kernel<<<dim3((ACC + 255) / 256), dim3(256), 0, stream>>>(ptot, pnz, out, nset);
}

// Round 5
// 119.510 us; speedup vs baseline: 1.1439x; 1.1439x over previous
//
#include <hip/hip_runtime.h>
#include <cmath>

#define NPIX   289          // 17*17
#define NU     10           // unique GLCM offsets (12 slots, 2 dups)
#define NF     70           // 4 stat + 6 hist + 60 glcm
#define NWX    60
#define IMG_W  256
#define IMG_HW 65536
#define NWIN   28800        // 8 * 60 * 60
#define ACC    560          // BATCH * NF
#define WPB    2            // waves per block
#define WPW    2            // windows per wave (ping-pong loads, batched atomics)
#define NBLK   (NWIN / (WPB * WPW))   // 7200
#define GLS    29           // padded LDS stride for 28-entry GLCM triangles

// slot -> unique offset index for the 12 reference offsets
__device__ __constant__ int c_s2u[12] = {0,1,2,3,4,1,5,3,6,7,8,9};

// unique offsets (dr, dc); flat-shift joff = dr*17 + dc
constexpr int JOFF[NU] = {1, 18, 17, 16, 2, 34, 3, 36, 51, 32};
// 1/(2*npairs), npairs = (17-dr)*(17-|dc|)
constexpr float INV2N[NU] = {1.f/544.f, 1.f/512.f, 1.f/544.f, 1.f/512.f, 1.f/510.f,
                             1.f/510.f, 1.f/476.f, 1.f/450.f, 1.f/476.f, 1.f/450.f};

// column-validity masks per distinct dc (target-column constraint).
struct CMs { unsigned m[10]; };
constexpr CMs mkcm(int dc) {
    CMs c{};
    for (int t = 0; t < NPIX; ++t) {
        int col = t % 17;
        bool ok = (dc > 0) ? (col >= dc) : (col <= 16 + dc);
        if (ok) c.m[t >> 5] |= 1u << (t & 31);
    }
    return c;
}
constexpr CMs CMp1 = mkcm(1), CMp2 = mkcm(2), CMp3 = mkcm(3);
constexpr CMs CMn1 = mkcm(-1), CMn2 = mkcm(-2);

// fused per-element constants for the upper-triangle feature pass.
struct alignas(32) FtE { float w, d2, inv, si, sii, sij, q0, q1; };
struct FtTab { FtE e[28]; };
constexpr FtTab mkft() {
    FtTab t{};
    int n = 0;
    for (int a = 1; a <= 7; ++a)
        for (int b = a; b <= 7; ++b) {
            int i = a - 1, j = b - 1;
            float w  = (a == b) ? 1.f : 2.f;
            float d2 = (float)((i - j) * (i - j));
            t.e[n] = FtE{w, d2, 1.f / (1.f + d2),
                         0.5f * (float)(i + j),
                         0.5f * (float)(i * i + j * j),
                         (float)(i * j), 0.f, 0.f};
            ++n;
        }
    return t;
}
__device__ __constant__ FtTab c_ft = mkft();

// GLCM pair count for one offset: popc(ma & shifted(mv)); word count pruned per offset.
template<int O>
__device__ __forceinline__ int gcnt(const unsigned* __restrict__ M,
                                    const unsigned* __restrict__ ma) {
    constexpr int wq = JOFF[O] >> 5;
    constexpr int rr = JOFF[O] & 31;
    constexpr int nw = (288 - JOFF[O]) / 32 + 1;
    int acc = 0;
#pragma unroll
    for (int w = 0; w < nw; ++w) {
        unsigned sh = (rr == 0) ? M[w + wq]
                                : __builtin_amdgcn_alignbit(M[w + wq + 1], M[w + wq], rr);
        acc += __popc(ma[w] & sh);
    }
    return acc;
}

// ---- DPP wave-64 reductions: 6 VALU ops, no LDS pipe ----
#define DPP_F(oldv, srcv, ctrl, rm) \
    __int_as_float(__builtin_amdgcn_update_dpp((oldv), __float_as_int(srcv), (ctrl), (rm), 0xF, false))

__device__ __forceinline__ float dpp_wsum(float v) {
    v += DPP_F(0, v, 0x111, 0xF);
    v += DPP_F(0, v, 0x112, 0xF);
    v += DPP_F(0, v, 0x114, 0xF);
    v += DPP_F(0, v, 0x118, 0xF);
    v += DPP_F(0, v, 0x142, 0xA);
    v += DPP_F(0, v, 0x143, 0xC);
    return __int_as_float(__builtin_amdgcn_readlane(__float_as_int(v), 63));
}
__device__ __forceinline__ float dpp_wmax(float v) {
    v = fmaxf(v, DPP_F(__float_as_int(v), v, 0x111, 0xF));
    v = fmaxf(v, DPP_F(__float_as_int(v), v, 0x112, 0xF));
    v = fmaxf(v, DPP_F(__float_as_int(v), v, 0x114, 0xF));
    v = fmaxf(v, DPP_F(__float_as_int(v), v, 0x118, 0xF));
    v = fmaxf(v, DPP_F(__float_as_int(v), v, 0x142, 0xA));
    v = fmaxf(v, DPP_F(__float_as_int(v), v, 0x143, 0xC));
    return __int_as_float(__builtin_amdgcn_readlane(__float_as_int(v), 63));
}
__device__ __forceinline__ float dpp_wmin(float v) {
    v = fminf(v, DPP_F(__float_as_int(v), v, 0x111, 0xF));
    v = fminf(v, DPP_F(__float_as_int(v), v, 0x112, 0xF));
    v = fminf(v, DPP_F(__float_as_int(v), v, 0x114, 0xF));
    v = fminf(v, DPP_F(__float_as_int(v), v, 0x118, 0xF));
    v = fminf(v, DPP_F(__float_as_int(v), v, 0x142, 0xA));
    v = fminf(v, DPP_F(__float_as_int(v), v, 0x143, 0xC));
    return __int_as_float(__builtin_amdgcn_readlane(__float_as_int(v), 63));
}

__device__ __forceinline__ float bperm_f(int addr, float v) {
    return __int_as_float(__builtin_amdgcn_ds_bpermute(addr, __float_as_int(v)));
}

__global__ __launch_bounds__(128, 8) void feat_kernel(const float* __restrict__ x,
                                                      float* __restrict__ ptot,
                                                      float* __restrict__ pnz,
                                                      int setmask) {
    __shared__ float s_g[WPB][NU * GLS];
    __shared__ float s_uf[WPB][5][NU];
    __shared__ float s_s10[WPB][10];

    const int lane = threadIdx.x & 63;
    const int wid  = threadIdx.x >> 6;
    const int gw    = blockIdx.x * WPB + wid;     // global wave id, 0..14399
    const int widx0 = gw * WPW;                    // even; pair never straddles batch/row
    const int b     = widx0 / 3600;
    const int rem0  = widx0 - b * 3600;
    const int wy    = rem0 / NWX;
    const int wx0   = rem0 - wy * NWX;             // even -> wx0+1 <= 59, no row wrap
    const float* img0 = x + (size_t)(b * 3 + 1) * IMG_HW + (wy * 4) * IMG_W + wx0 * 4;

    float* gl  = s_g[wid];
    float (*uf)[NU] = s_uf[wid];
    float* s10 = s_s10[wid];

    // ---- wave-invariant lane mappings (amortized over both windows) ----
    const int l49 = (lane < 49) ? lane : 48;
    const int ba  = l49 / 7 + 1;
    const int bb  = l49 - (ba - 1) * 7 + 1;
    const int partner = (bb - 1) * 7 + (ba - 1);
    const int paddr   = partner << 2;
    const unsigned long long xm0a = (ba & 1) ? 0ull : ~0ull;
    const unsigned long long xm1a = (ba & 2) ? 0ull : ~0ull;
    const unsigned long long xm2a = (ba & 4) ? 0ull : ~0ull;
    const int amin  = min(ba, bb);
    const int idx28 = 8 * (amin - 1) - ((amin * (amin - 1)) >> 1) + (max(ba, bb) - amin);
    const bool wr   = (lane < 49) && (ba <= bb);
    const int fo  = lane & 15;
    const int sub = lane >> 4;
    const int xa16 = (lane ^ 16) << 2;
    const int xa32 = (lane ^ 32) << 2;

    // readback pointers for the two output slots this lane owns (t=lane, t=lane+64)
    const float* rb0;
    if (lane < 10) {
        rb0 = &s10[lane];
    } else {
        int u = lane - 10, g = u / 12;
        rb0 = &uf[g][c_s2u[u - g * 12]];
    }
    const int u1 = (lane < 6) ? (lane + 54) : 54;   // t=lane+64 -> u in 54..59 (lanes 0..5)
    const int g1 = u1 / 12;                          // == 4
    const float* rb1 = &uf[g1][c_s2u[u1 - g1 * 12]];

    // per-lane image offsets (shared by both windows; window 1 is +4 floats)
    int off[5];
#pragma unroll
    for (int k = 0; k < 5; ++k) {
        int t = lane + k * 64;
        int r = t / 17;
        off[k] = r * (IMG_W - 17) + t;     // == r*256 + col
    }
    const bool v4 = (lane < NPIX - 256);   // k=4 validity (lane < 33)

    float facc0 = 0.f, facc1 = 0.f, nzh = 0.f, wcnt = 0.f;

    auto PROC = [&](const float (&pv)[5]) {
        float lsum = 0.f, lss = 0.f, lmax = -1e30f, lmin = 1e30f;
        int n = 0, c1 = 0, c2 = 0, c3 = 0, c4 = 0, c5 = 0, c6 = 0;
        unsigned ma32[10];
#pragma unroll
        for (int k = 0; k < 5; ++k) {
            float p = pv[k];
            float val = (p < 10.f) ? 0.f : p;
            if (k == 4) val = v4 ? val : 0.f;          // out-of-window lanes contribute 0
            int qq = (int)fmaf(val, 0.025f, 0.8125f);  // 0..7, 0 iff val==0
            lsum += val;
            float d = (val != 0.f) ? (val - 127.5f) : 0.f;
            lss = fmaf(d, d, lss);
            lmax = fmaxf(lmax, val);
            lmin = fminf(lmin, (val != 0.f) ? val : 1e30f);
            unsigned long long p0 = __ballot(qq & 1);
            unsigned long long p1 = __ballot(qq & 2);
            unsigned long long p2 = __ballot(qq & 4);
            n  += __popcll(p0 | p1 | p2);
            c1 += __popcll(p0 & ~p1 & ~p2);
            c2 += __popcll(~p0 & p1 & ~p2);
            c3 += __popcll(p0 & p1 & ~p2);
            c4 += __popcll(~p0 & ~p1 & p2);
            c5 += __popcll(p0 & ~p1 & p2);
            c6 += __popcll(~p0 & p1 & p2);
            unsigned long long mA = (p0 ^ xm0a) & (p1 ^ xm1a) & (p2 ^ xm2a);
            ma32[2*k]   = (unsigned)mA;
            ma32[2*k+1] = (unsigned)(mA >> 32);
        }

        if (n == 0) return;   // empty window contributes nothing
        wcnt += 1.f;

        // mB fetch on the LDS pipe; latency hides under the DPP stat reductions
        unsigned mv0[10];
#pragma unroll
        for (int w = 0; w < 10; ++w)
            mv0[w] = (unsigned)__builtin_amdgcn_ds_bpermute(paddr, (int)ma32[w]);

        const float fn   = (float)n;
        const float sum  = dpp_wsum(lsum);
        const float ss   = dpp_wsum(lss);
        const float mx   = dpp_wmax(lmax);
        const float mn   = dpp_wmin(lmin);
        const float mean = sum / fn;
        const float mc   = mean - 127.5f;
        const float var  = fmaxf(ss / fn - mc * mc, 0.f);
        const float stdv = sqrtf(var);

        if (lane == 0) {
            s10[0] = mean;
            s10[1] = stdv;
            s10[2] = (mx - mean) / (stdv + 1e-9f);
            s10[3] = (mean - mn) / (stdv + 1e-9f);
            s10[4] = (float)c1 * (1.f / 289.f);
            s10[5] = (float)c2 * (1.f / 289.f);
            s10[6] = (float)c3 * (1.f / 289.f);
            s10[7] = (float)c4 * (1.f / 289.f);
            s10[8] = (float)c5 * (1.f / 289.f);
            s10[9] = (float)c6 * (1.f / 289.f);
        }

        // GLCM counts: column-masked mv0, shared per distinct dc
        int cnta[NU];
        {
            cnta[2] = gcnt<2>(mv0, ma32);
            cnta[5] = gcnt<5>(mv0, ma32);
            cnta[8] = gcnt<8>(mv0, ma32);
            unsigned mv[10];
#pragma unroll
            for (int w = 0; w < 10; ++w) mv[w] = mv0[w] & CMp1.m[w];
            cnta[0] = gcnt<0>(mv, ma32);
            cnta[1] = gcnt<1>(mv, ma32);
#pragma unroll
            for (int w = 0; w < 10; ++w) mv[w] = mv0[w] & CMp2.m[w];
            cnta[4] = gcnt<4>(mv, ma32);
            cnta[7] = gcnt<7>(mv, ma32);
#pragma unroll
            for (int w = 0; w < 10; ++w) mv[w] = mv0[w] & CMp3.m[w];
            cnta[6] = gcnt<6>(mv, ma32);
#pragma unroll
            for (int w = 0; w < 10; ++w) mv[w] = mv0[w] & CMn1.m[w];
            cnta[3] = gcnt<3>(mv, ma32);
#pragma unroll
            for (int w = 0; w < 10; ++w) mv[w] = mv0[w] & CMn2.m[w];
            cnta[9] = gcnt<9>(mv, ma32);
        }

        // symmetrize via bpermute, stage upper triangle into LDS
#pragma unroll
        for (int o = 0; o < NU; ++o) {
            int pc = __builtin_amdgcn_ds_bpermute(paddr, cnta[o]);
            float g = (float)(cnta[o] + pc) * INV2N[o];
            if (wr) gl[o * GLS + idx28] = g;
        }

        // features over upper triangle: 4 sub-lanes per offset, 7 iters
        float gsum=0.f, entU=0.f, conU=0.f, homU=0.f, g2=0.f, siU=0.f, siiU=0.f, sijU=0.f;
        if (fo < NU) {
#pragma unroll
            for (int i = 0; i < 7; ++i) {
                const int e = sub + 4 * i;
                FtE c = c_ft.e[e];
                float g  = gl[fo * GLS + e];
                float gw = g * c.w;
                float l  = __log2f(g + 1e-8f);
                gsum += gw;
                entU  = fmaf(gw, l,      entU);
                conU  = fmaf(gw, c.d2,   conU);
                homU  = fmaf(gw, c.inv,  homU);
                g2    = fmaf(gw, g,      g2);
                siU   = fmaf(gw, c.si,   siU);
                siiU  = fmaf(gw, c.sii,  siiU);
                sijU  = fmaf(gw, c.sij,  sijU);
            }
        }
        gsum += bperm_f(xa16, gsum);  entU += bperm_f(xa16, entU);
        conU += bperm_f(xa16, conU);  homU += bperm_f(xa16, homU);
        g2   += bperm_f(xa16, g2);    siU  += bperm_f(xa16, siU);
        siiU += bperm_f(xa16, siiU);  sijU += bperm_f(xa16, sijU);
        gsum += bperm_f(xa32, gsum);  entU += bperm_f(xa32, entU);
        conU += bperm_f(xa32, conU);  homU += bperm_f(xa32, homU);
        g2   += bperm_f(xa32, g2);    siU  += bperm_f(xa32, siU);
        siiU += bperm_f(xa32, siiU);  sijU += bperm_f(xa32, sijU);

        if (fo < NU && sub == 0) {
            const float invg = 1.f / fmaxf(gsum, 1e-12f);
            const float si  = siU  * invg;
            const float sii = siiU * invg;
            const float sij = sijU * invg;
            const float varg = fmaxf(sii - si * si, 0.f);
            const float cov  = sij - si * si;
            uf[0][fo] = conU * invg;
            uf[1][fo] = homU * invg;
            uf[2][fo] = sqrtf(g2) * invg;
            uf[3][fo] = (varg < 1e-15f) ? 1.f : cov / fmaxf(varg, 1e-15f);
            uf[4][fo] = -entU;
        }

        // readback this window's two feature slots into register accumulators
        float f0 = *rb0;
        facc0 += f0;
        if (lane >= 4 && lane <= 9) nzh += (f0 != 0.f) ? 1.f : 0.f;
        if (lane < 6) facc1 += *rb1;
    };

    // ---- both windows' loads issued up-front; window 1's latency hides under PROC(0) ----
    float bufA[5], bufB[5];
    {
        const float* ipA = img0;
        const float* ipB = img0 + 4;
        bufA[0] = ipA[off[0]]; bufA[1] = ipA[off[1]]; bufA[2] = ipA[off[2]];
        bufA[3] = ipA[off[3]]; bufA[4] = ipA[off[4]];
        bufB[0] = ipB[off[0]]; bufB[1] = ipB[off[1]]; bufB[2] = ipB[off[2]];
        bufB[3] = ipB[off[3]]; bufB[4] = ipB[off[4]];
    }
    PROC(bufA);
    PROC(bufB);

    // ---- single batched atomic set per wave (one vmcnt drain per 2 windows) ----
    const int setbase = (gw & setmask) * ACC + b * NF;
    atomicAdd(&ptot[setbase + lane], facc0);
    if (lane < 6) atomicAdd(&ptot[setbase + 64 + lane], facc1);
    if (lane >= 4 && lane <= 9 && nzh != 0.f) atomicAdd(&pnz[setbase + lane], nzh);
    if (lane == 0 && wcnt != 0.f) atomicAdd(&pnz[setbase], wcnt);
}

__global__ void reduce_kernel(const float* __restrict__ ptot,
                              const float* __restrict__ pnz,
                              float* __restrict__ out, int nset) {
    int t = blockIdx.x * blockDim.x + threadIdx.x;
    if (t >= ACC) return;
    int b = t / NF;
    int u = t - b * NF;
    bool hist = (u >= 4 && u <= 9);
    int nzidx = hist ? t : b * NF;       // hardwired features use the window count
    float s = 0.f, nz = 0.f;
    for (int k = 0; k < nset; ++k) {
        s  += ptot[(size_t)k * ACC + t];
        nz += pnz[(size_t)k * ACC + nzidx];
    }
    out[t] = s / (nz + 1e-9f);
}

extern "C" void kernel_launch(void* const* d_in, const int* in_sizes, int n_in,
                              void* d_out, int out_size, void* d_ws, size_t ws_size,
                              hipStream_t stream) {
    (void)in_sizes; (void)n_in; (void)out_size;
    const float* x = (const float*)d_in[0];
    float* out = (float*)d_out;

    const size_t per_set = (size_t)2 * ACC * sizeof(float);   // 4480 B
    int maxs = (ws_size >= per_set) ? (int)(ws_size / per_set) : 1;
    int nset = 1;
    while ((nset * 2) <= maxs && nset < 64) nset <<= 1;

    float* ptot = (float*)d_ws;
    float* pnz  = ptot + (size_t)nset * ACC;

    hipMemsetAsync(d_ws, 0, (size_t)nset * per_set, stream);
    feat_kernel<<<dim3(NBLK), dim3(WPB * 64), 0, stream>>>(x, ptot, pnz, nset - 1);
    reduce_kernel<<<dim3((ACC + 255) / 256), dim3(256), 0, stream>>>(ptot, pnz, out, nset);
}

// Round 6
// 113.801 us; speedup vs baseline: 1.2013x; 1.0502x over previous
//
#include <hip/hip_runtime.h>
#include <cmath>

#define NPIX   289          // 17*17
#define NU     10           // unique GLCM offsets (12 slots, 2 dups)
#define NF     70           // 4 stat + 6 hist + 60 glcm
#define NWX    60
#define IMG_W  256
#define IMG_HW 65536
#define NWIN   28800        // 8 * 60 * 60
#define ACC    560          // BATCH * NF
#define WPB    2            // waves per block (R3-proven local optimum)
#define NBLK   (NWIN / WPB) // 14400
#define GLS    29           // padded LDS stride for 28-entry GLCM triangles

// slot -> unique offset index for the 12 reference offsets
__device__ __constant__ int c_s2u[12] = {0,1,2,3,4,1,5,3,6,7,8,9};

// unique offsets (dr, dc); flat-shift joff = dr*17 + dc
constexpr int JOFF[NU] = {1, 18, 17, 16, 2, 34, 3, 36, 51, 32};
// 1/(2*npairs), npairs = (17-dr)*(17-|dc|)
constexpr float INV2N[NU] = {1.f/544.f, 1.f/512.f, 1.f/544.f, 1.f/512.f, 1.f/510.f,
                             1.f/510.f, 1.f/476.f, 1.f/450.f, 1.f/476.f, 1.f/450.f};

// column-validity masks per distinct dc (target-column constraint).
struct CMs { unsigned m[10]; };
constexpr CMs mkcm(int dc) {
    CMs c{};
    for (int t = 0; t < NPIX; ++t) {
        int col = t % 17;
        bool ok = (dc > 0) ? (col >= dc) : (col <= 16 + dc);
        if (ok) c.m[t >> 5] |= 1u << (t & 31);
    }
    return c;
}
constexpr CMs CMp1 = mkcm(1), CMp2 = mkcm(2), CMp3 = mkcm(3);
constexpr CMs CMn1 = mkcm(-1), CMn2 = mkcm(-2);

// fused per-element constants for the upper-triangle feature pass.
struct alignas(32) FtE { float w, d2, inv, si, sii, sij, q0, q1; };
struct FtTab { FtE e[28]; };
constexpr FtTab mkft() {
    FtTab t{};
    int n = 0;
    for (int a = 1; a <= 7; ++a)
        for (int b = a; b <= 7; ++b) {
            int i = a - 1, j = b - 1;
            float w  = (a == b) ? 1.f : 2.f;
            float d2 = (float)((i - j) * (i - j));
            t.e[n] = FtE{w, d2, 1.f / (1.f + d2),
                         0.5f * (float)(i + j),
                         0.5f * (float)(i * i + j * j),
                         (float)(i * j), 0.f, 0.f};
            ++n;
        }
    return t;
}
__device__ __constant__ FtTab c_ft = mkft();

// GLCM pair count for one offset: popc(ma & shifted(mv)); word count pruned per offset.
template<int O>
__device__ __forceinline__ int gcnt(const unsigned* __restrict__ M,
                                    const unsigned* __restrict__ ma) {
    constexpr int wq = JOFF[O] >> 5;
    constexpr int rr = JOFF[O] & 31;
    constexpr int nw = (288 - JOFF[O]) / 32 + 1;
    int acc = 0;
#pragma unroll
    for (int w = 0; w < nw; ++w) {
        unsigned sh = (rr == 0) ? M[w + wq]
                                : __builtin_amdgcn_alignbit(M[w + wq + 1], M[w + wq], rr);
        acc += __popc(ma[w] & sh);
    }
    return acc;
}

// ---- DPP wave-64 reductions: 6 VALU ops, no LDS pipe ----
#define DPP_F(oldv, srcv, ctrl, rm) \
    __int_as_float(__builtin_amdgcn_update_dpp((oldv), __float_as_int(srcv), (ctrl), (rm), 0xF, false))

__device__ __forceinline__ float dpp_wsum(float v) {
    v += DPP_F(0, v, 0x111, 0xF);
    v += DPP_F(0, v, 0x112, 0xF);
    v += DPP_F(0, v, 0x114, 0xF);
    v += DPP_F(0, v, 0x118, 0xF);
    v += DPP_F(0, v, 0x142, 0xA);
    v += DPP_F(0, v, 0x143, 0xC);
    return __int_as_float(__builtin_amdgcn_readlane(__float_as_int(v), 63));
}
__device__ __forceinline__ float dpp_wmax(float v) {
    v = fmaxf(v, DPP_F(__float_as_int(v), v, 0x111, 0xF));
    v = fmaxf(v, DPP_F(__float_as_int(v), v, 0x112, 0xF));
    v = fmaxf(v, DPP_F(__float_as_int(v), v, 0x114, 0xF));
    v = fmaxf(v, DPP_F(__float_as_int(v), v, 0x118, 0xF));
    v = fmaxf(v, DPP_F(__float_as_int(v), v, 0x142, 0xA));
    v = fmaxf(v, DPP_F(__float_as_int(v), v, 0x143, 0xC));
    return __int_as_float(__builtin_amdgcn_readlane(__float_as_int(v), 63));
}
__device__ __forceinline__ float dpp_wmin(float v) {
    v = fminf(v, DPP_F(__float_as_int(v), v, 0x111, 0xF));
    v = fminf(v, DPP_F(__float_as_int(v), v, 0x112, 0xF));
    v = fminf(v, DPP_F(__float_as_int(v), v, 0x114, 0xF));
    v = fminf(v, DPP_F(__float_as_int(v), v, 0x118, 0xF));
    v = fminf(v, DPP_F(__float_as_int(v), v, 0x142, 0xA));
    v = fminf(v, DPP_F(__float_as_int(v), v, 0x143, 0xC));
    return __int_as_float(__builtin_amdgcn_readlane(__float_as_int(v), 63));
}

__device__ __forceinline__ float bperm_f(int addr, float v) {
    return __int_as_float(__builtin_amdgcn_ds_bpermute(addr, __float_as_int(v)));
}

__global__ __launch_bounds__(128, 8) void feat_kernel(const float* __restrict__ x,
                                                      float* __restrict__ ptot,
                                                      float* __restrict__ pnz,
                                                      int setmask) {
    __shared__ float s_g[WPB][NU * GLS];
    __shared__ float s_uf[WPB][5][NU];
    __shared__ float s_s10[WPB][10];

    const int lane = threadIdx.x & 63;
    const int wid  = threadIdx.x >> 6;
    const int widx = blockIdx.x * WPB + wid;
    const int b    = widx / 3600;
    const int rem  = widx - b * 3600;
    const int wy   = rem / NWX;
    const int wx   = rem - wy * NWX;
    const float* img = x + (size_t)(b * 3 + 1) * IMG_HW + (wy * 4) * IMG_W + wx * 4;

    float* gl  = s_g[wid];
    float (*uf)[NU] = s_uf[wid];
    float* s10 = s_s10[wid];

    // lane -> (a,b) bin pair for the GLCM phase
    const int l49 = (lane < 49) ? lane : 48;
    const int ba  = l49 / 7 + 1;
    const int bb  = l49 - (ba - 1) * 7 + 1;
    const int partner = (bb - 1) * 7 + (ba - 1);
    const int paddr   = partner << 2;
    const unsigned long long xm0a = (ba & 1) ? 0ull : ~0ull;
    const unsigned long long xm1a = (ba & 2) ? 0ull : ~0ull;
    const unsigned long long xm2a = (ba & 4) ? 0ull : ~0ull;

    // ---- pass A: branchless loads (k=4 lanes >=33 masked; max index verified in-bounds),
    //      threshold, quantize, stats; ballots consumed per-k ----
    float lsum = 0.f, lss = 0.f, lmax = -1e30f, lmin = 1e30f;
    int n = 0, c1 = 0, c2 = 0, c3 = 0, c4 = 0, c5 = 0, c6 = 0;
    unsigned ma32[10];
    const bool v4 = (lane < NPIX - 256);   // k=4 validity (lane < 33)
#pragma unroll
    for (int k = 0; k < 5; ++k) {
        const int t = lane + k * 64;
        const int r = t / 17;
        float p = img[r * (IMG_W - 17) + t];           // r*256 + c == r*239 + t
        float val = (p < 10.f) ? 0.f : p;
        if (k == 4) val = v4 ? val : 0.f;              // out-of-window lanes contribute 0
        // quantize: val in {0} U [10,255] -> qq = (int)(val/40 + 0.8125) in 0..7
        int qq = (int)fmaf(val, 0.025f, 0.8125f);
        lsum += val;
        float d = (val != 0.f) ? (val - 127.5f) : 0.f;
        lss = fmaf(d, d, lss);
        lmax = fmaxf(lmax, val);                       // zeros can't win (max>=10)
        lmin = fminf(lmin, (val != 0.f) ? val : 1e30f);
        unsigned long long p0 = __ballot(qq & 1);
        unsigned long long p1 = __ballot(qq & 2);
        unsigned long long p2 = __ballot(qq & 4);
        n  += __popcll(p0 | p1 | p2);
        c1 += __popcll(p0 & ~p1 & ~p2);
        c2 += __popcll(~p0 & p1 & ~p2);
        c3 += __popcll(p0 & p1 & ~p2);
        c4 += __popcll(~p0 & ~p1 & p2);
        c5 += __popcll(p0 & ~p1 & p2);
        c6 += __popcll(~p0 & p1 & p2);
        unsigned long long mA = (p0 ^ xm0a) & (p1 ^ xm1a) & (p2 ^ xm2a);
        ma32[2*k]   = (unsigned)mA;
        ma32[2*k+1] = (unsigned)(mA >> 32);
    }

    if (n == 0) return;   // all-zero window contributes nothing (no barriers in this kernel)

    // ---- issue mB fetch early (LDS pipe); latency hides under the DPP stat reductions ----
    unsigned mv0[10];
#pragma unroll
    for (int w = 0; w < 10; ++w)
        mv0[w] = (unsigned)__builtin_amdgcn_ds_bpermute(paddr, (int)ma32[w]);

    const float fn   = (float)n;
    const float sum  = dpp_wsum(lsum);
    const float ss   = dpp_wsum(lss);
    const float mx   = dpp_wmax(lmax);
    const float mn   = dpp_wmin(lmin);
    const float mean = sum / fn;
    const float mc   = mean - 127.5f;
    const float var  = fmaxf(ss / fn - mc * mc, 0.f);
    const float stdv = sqrtf(var);

    if (lane == 0) {
        s10[0] = mean;
        s10[1] = stdv;
        s10[2] = (mx - mean) / (stdv + 1e-9f);
        s10[3] = (mean - mn) / (stdv + 1e-9f);
        s10[4] = (float)c1 * (1.f / 289.f);
        s10[5] = (float)c2 * (1.f / 289.f);
        s10[6] = (float)c3 * (1.f / 289.f);
        s10[7] = (float)c4 * (1.f / 289.f);
        s10[8] = (float)c5 * (1.f / 289.f);
        s10[9] = (float)c6 * (1.f / 289.f);
    }

    // ---- GLCM counts: column-masked mv0, shared per distinct dc ----
    int cnta[NU];
    {
        // dc == 0 offsets use mv0 directly (also first users -> covers bpermute wait)
        cnta[2] = gcnt<2>(mv0, ma32);
        cnta[5] = gcnt<5>(mv0, ma32);
        cnta[8] = gcnt<8>(mv0, ma32);
        unsigned mv[10];
#pragma unroll
        for (int w = 0; w < 10; ++w) mv[w] = mv0[w] & CMp1.m[w];
        cnta[0] = gcnt<0>(mv, ma32);
        cnta[1] = gcnt<1>(mv, ma32);
#pragma unroll
        for (int w = 0; w < 10; ++w) mv[w] = mv0[w] & CMp2.m[w];
        cnta[4] = gcnt<4>(mv, ma32);
        cnta[7] = gcnt<7>(mv, ma32);
#pragma unroll
        for (int w = 0; w < 10; ++w) mv[w] = mv0[w] & CMp3.m[w];
        cnta[6] = gcnt<6>(mv, ma32);
#pragma unroll
        for (int w = 0; w < 10; ++w) mv[w] = mv0[w] & CMn1.m[w];
        cnta[3] = gcnt<3>(mv, ma32);
#pragma unroll
        for (int w = 0; w < 10; ++w) mv[w] = mv0[w] & CMn2.m[w];
        cnta[9] = gcnt<9>(mv, ma32);
    }

    // ---- symmetrize via bpermute, stage upper triangle into LDS ----
    const int amin  = min(ba, bb);
    const int idx28 = 8 * (amin - 1) - ((amin * (amin - 1)) >> 1) + (max(ba, bb) - amin);
    const bool wr   = (lane < 49) && (ba <= bb);
#pragma unroll
    for (int o = 0; o < NU; ++o) {
        int pc = __builtin_amdgcn_ds_bpermute(paddr, cnta[o]);
        float g = (float)(cnta[o] + pc) * INV2N[o];
        if (wr) gl[o * GLS + idx28] = g;
    }

    // ---- features over upper triangle: 4 sub-lanes per offset, 7 iters ----
    const int fo  = lane & 15;
    const int sub = lane >> 4;
    float gsum=0.f, entU=0.f, conU=0.f, homU=0.f, g2=0.f, siU=0.f, siiU=0.f, sijU=0.f;
    if (fo < NU) {
#pragma unroll
        for (int i = 0; i < 7; ++i) {
            const int e = sub + 4 * i;
            FtE c = c_ft.e[e];
            float g  = gl[fo * GLS + e];
            float gw = g * c.w;
            float l  = __log2f(g + 1e-8f);
            gsum += gw;
            entU  = fmaf(gw, l,      entU);
            conU  = fmaf(gw, c.d2,   conU);
            homU  = fmaf(gw, c.inv,  homU);
            g2    = fmaf(gw, g,      g2);
            siU   = fmaf(gw, c.si,   siU);
            siiU  = fmaf(gw, c.sii,  siiU);
            sijU  = fmaf(gw, c.sij,  sijU);
        }
    }
    const int xa16 = (lane ^ 16) << 2;
    const int xa32 = (lane ^ 32) << 2;
    gsum += bperm_f(xa16, gsum);  entU += bperm_f(xa16, entU);
    conU += bperm_f(xa16, conU);  homU += bperm_f(xa16, homU);
    g2   += bperm_f(xa16, g2);    siU  += bperm_f(xa16, siU);
    siiU += bperm_f(xa16, siiU);  sijU += bperm_f(xa16, sijU);
    gsum += bperm_f(xa32, gsum);  entU += bperm_f(xa32, entU);
    conU += bperm_f(xa32, conU);  homU += bperm_f(xa32, homU);
    g2   += bperm_f(xa32, g2);    siU  += bperm_f(xa32, siU);
    siiU += bperm_f(xa32, siiU);  sijU += bperm_f(xa32, sijU);

    if (fo < NU && sub == 0) {
        const float invg = 1.f / fmaxf(gsum, 1e-12f);
        const float si  = siU  * invg;
        const float sii = siiU * invg;
        const float sij = sijU * invg;
        const float varg = fmaxf(sii - si * si, 0.f);
        const float cov  = sij - si * si;
        uf[0][fo] = conU * invg;
        uf[1][fo] = homU * invg;
        uf[2][fo] = sqrtf(g2) * invg;
        uf[3][fo] = (varg < 1e-15f) ? 1.f : cov / fmaxf(varg, 1e-15f);
        uf[4][fo] = -entU;
    }

    // ---- per-window atomic tail (R3 timing), unrolled with hoisted slot pointers ----
    // slot t=lane: s10[lane] for lane<10, else uf[grp][c_s2u[slot]]
    const float* rb0;
    if (lane < 10) {
        rb0 = &s10[lane];
    } else {
        int u = lane - 10, g = u / 12;
        rb0 = &uf[g][c_s2u[u - g * 12]];
    }
    // slot t=lane+64 (lanes 0..5 only): u=lane+54, grp=4, slot-in-grp=lane+6
    const float* rb1 = &uf[4][c_s2u[(lane < 6 ? lane : 0) + 6]];

    const int base = (widx & setmask) * ACC + b * NF;
    float f0 = *rb0;
    atomicAdd(&ptot[base + lane], f0);
    if (lane < 6) atomicAdd(&ptot[base + 64 + lane], *rb1);
    if (lane >= 4 && lane <= 9 && f0 != 0.f) atomicAdd(&pnz[base + lane], 1.f);
    if (lane == 0) atomicAdd(&pnz[base], 1.f);   // window count (n>0)
}

__global__ void reduce_kernel(const float* __restrict__ ptot,
                              const float* __restrict__ pnz,
                              float* __restrict__ out, int nset) {
    int t = blockIdx.x * blockDim.x + threadIdx.x;
    if (t >= ACC) return;
    int b = t / NF;
    int u = t - b * NF;
    bool hist = (u >= 4 && u <= 9);
    int nzidx = hist ? t : b * NF;       // hardwired features use the window count
    float s = 0.f, nz = 0.f;
    for (int k = 0; k < nset; ++k) {
        s  += ptot[(size_t)k * ACC + t];
        nz += pnz[(size_t)k * ACC + nzidx];
    }
    out[t] = s / (nz + 1e-9f);
}

extern "C" void kernel_launch(void* const* d_in, const int* in_sizes, int n_in,
                              void* d_out, int out_size, void* d_ws, size_t ws_size,
                              hipStream_t stream) {
    (void)in_sizes; (void)n_in; (void)out_size;
    const float* x = (const float*)d_in[0];
    float* out = (float*)d_out;

    const size_t per_set = (size_t)2 * ACC * sizeof(float);   // 4480 B
    int maxs = (ws_size >= per_set) ? (int)(ws_size / per_set) : 1;
    int nset = 1;
    while ((nset * 2) <= maxs && nset < 64) nset <<= 1;

    float* ptot = (float*)d_ws;
    float* pnz  = ptot + (size_t)nset * ACC;

    hipMemsetAsync(d_ws, 0, (size_t)nset * per_set, stream);
    feat_kernel<<<dim3(NBLK), dim3(WPB * 64), 0, stream>>>(x, ptot, pnz, nset - 1);
    reduce_kernel<<<dim3((ACC + 255) / 256), dim3(256), 0, stream>>>(ptot, pnz, out, nset);
}